// Round 1
// baseline (1056.323 us; speedup 1.0000x reference)
//
#include <hip/hip_runtime.h>

#define N_NODES 100000
#define N_EDGES 1600000
#define D 64
#define N_GRAPHS 64

// ---------------- degree / normalization ----------------

__global__ void k_init_deg(float* __restrict__ deg) {
    int i = blockIdx.x * blockDim.x + threadIdx.x;
    if (i < N_NODES) deg[i] = 1.0f;   // self-loop weight
}

__global__ void k_edge_deg(const int* __restrict__ dst, const float* __restrict__ ew,
                           float* __restrict__ deg) {
    int e = blockIdx.x * blockDim.x + threadIdx.x;
    if (e < N_EDGES) atomicAdd(&deg[dst[e]], ew[e]);
}

__global__ void k_dinv(float* __restrict__ deg) {
    int i = blockIdx.x * blockDim.x + threadIdx.x;
    if (i < N_NODES) {
        float d = deg[i];
        deg[i] = d > 0.f ? rsqrtf(d) : 0.f;
    }
}

// ---------------- dense 64x64 GEMM: out[row][c] = sum_k in'[row][k] * W[k][c] ----
// in' = FUSE ? relu(in + bias) : in.  One wave per row; W staged in LDS.

template <bool FUSE_RELU_BIAS>
__global__ void k_gemm(const float* __restrict__ in, const float* __restrict__ W,
                       const float* __restrict__ bias, float* __restrict__ out) {
    __shared__ float Ws[D * D];
    for (int i = threadIdx.x; i < D * D; i += blockDim.x) Ws[i] = W[i];
    __syncthreads();

    const int lane = threadIdx.x & 63;
    const int wib  = threadIdx.x >> 6;
    const int wpb  = blockDim.x >> 6;
    const int gwid = blockIdx.x * wpb + wib;
    const int tw   = gridDim.x * wpb;

    float bl = 0.f;
    if (FUSE_RELU_BIAS) bl = bias[lane];

    for (int row = gwid; row < N_NODES; row += tw) {
        float xv = in[row * D + lane];
        if (FUSE_RELU_BIAS) xv = fmaxf(xv + bl, 0.f);
        float acc = 0.f;
#pragma unroll
        for (int k = 0; k < D; ++k) {
            float xk = __shfl(xv, k);
            acc = fmaf(xk, Ws[k * D + lane], acc);
        }
        out[row * D + lane] = acc;
    }
}

// ---------------- aggregation ----------------
// init: agg[i][d] = h[i][d] * dinv[i]^2   (self-loop, doubles as zero-init)
__global__ void k_agg_init(const float* __restrict__ h, const float* __restrict__ dinv,
                           float* __restrict__ agg) {
    int idx = blockIdx.x * blockDim.x + threadIdx.x;
    const int total = N_NODES * D;
    const int stride = gridDim.x * blockDim.x;
    for (; idx < total; idx += stride) {
        int i = idx >> 6;
        float w = dinv[i];
        agg[idx] = h[idx] * (w * w);
    }
}

// edges: agg[dst][d] += h[src][d] * (dinv[src]*ew*dinv[dst]);  one wave per edge
__global__ void k_agg_edges(const int* __restrict__ src, const int* __restrict__ dst,
                            const float* __restrict__ ew, const float* __restrict__ dinv,
                            const float* __restrict__ h, float* __restrict__ agg) {
    const int lane = threadIdx.x & 63;
    int gwid = (blockIdx.x * blockDim.x + threadIdx.x) >> 6;
    const int tw = (gridDim.x * blockDim.x) >> 6;
    for (int e = gwid; e < N_EDGES; e += tw) {
        int s = src[e];
        int d = dst[e];
        float nrm = dinv[s] * ew[e] * dinv[d];
        float v = h[s * D + lane] * nrm;
        atomicAdd(&agg[d * D + lane], v);
    }
}

// ---------------- global mean pool ----------------
// batch is sorted; block g binary-searches its [start,end) range. No atomics.
__global__ void k_pool(const float* __restrict__ agg, const float* __restrict__ bias,
                       const int* __restrict__ batch, float* __restrict__ out) {
    const int g = blockIdx.x;

    int lo = 0, hi = N_NODES;
    while (lo < hi) { int mid = (lo + hi) >> 1; if (batch[mid] < g) lo = mid + 1; else hi = mid; }
    const int start = lo;
    hi = N_NODES;
    while (lo < hi) { int mid = (lo + hi) >> 1; if (batch[mid] < g + 1) lo = mid + 1; else hi = mid; }
    const int end = lo;

    const int lane = threadIdx.x & 63;
    const int w = threadIdx.x >> 6;
    const float bl = bias[lane];

    float acc = 0.f;
    for (int i = start + w; i < end; i += 4) {
        acc += fmaxf(agg[i * D + lane] + bl, 0.f);
    }

    __shared__ float red[4][D];
    red[w][lane] = acc;
    __syncthreads();
    if (w == 0) {
        float s = red[0][lane] + red[1][lane] + red[2][lane] + red[3][lane];
        float cnt = (float)(end - start);
        out[g * D + lane] = s / fmaxf(cnt, 1.0f);
    }
}

// ---------------- launch ----------------

extern "C" void kernel_launch(void* const* d_in, const int* in_sizes, int n_in,
                              void* d_out, int out_size, void* d_ws, size_t ws_size,
                              hipStream_t stream) {
    const float* x     = (const float*)d_in[0];
    const int*   ei    = (const int*)d_in[1];
    const int*   src   = ei;               // edge_index[0]
    const int*   dst   = ei + N_EDGES;     // edge_index[1]
    const int*   batch = (const int*)d_in[2];
    const float* ew    = (const float*)d_in[3];
    const float* W1    = (const float*)d_in[4];
    const float* b1    = (const float*)d_in[5];
    const float* W2    = (const float*)d_in[6];
    const float* b2    = (const float*)d_in[7];
    float* out = (float*)d_out;

    char* ws = (char*)d_ws;
    float* bufA = (float*)ws;                       // h   (25.6 MB)
    float* bufB = (float*)(ws + 25600000);          // agg (25.6 MB)
    float* deg  = (float*)(ws + 51200000);          // deg/dinv (400 KB)

    // normalization
    k_init_deg<<<(N_NODES + 255) / 256, 256, 0, stream>>>(deg);
    k_edge_deg<<<(N_EDGES + 255) / 256, 256, 0, stream>>>(dst, ew, deg);
    k_dinv<<<(N_NODES + 255) / 256, 256, 0, stream>>>(deg);

    // layer 1: h1 = x @ W1 ; agg1 = A_norm h1
    k_gemm<false><<<1024, 256, 0, stream>>>(x, W1, b1, bufA);
    k_agg_init<<<4096, 256, 0, stream>>>(bufA, deg, bufB);
    k_agg_edges<<<2048, 256, 0, stream>>>(src, dst, ew, deg, bufA, bufB);

    // layer 2: h2 = relu(agg1 + b1) @ W2 ; agg2 = A_norm h2
    k_gemm<true><<<1024, 256, 0, stream>>>(bufB, W2, b1, bufA);
    k_agg_init<<<4096, 256, 0, stream>>>(bufA, deg, bufB);
    k_agg_edges<<<2048, 256, 0, stream>>>(src, dst, ew, deg, bufA, bufB);

    // pool: out[g] = mean over graph g of relu(agg2 + b2)
    k_pool<<<N_GRAPHS, 256, 0, stream>>>(bufB, b2, batch, out);
}

// Round 2
// 887.955 us; speedup vs baseline: 1.1896x; 1.1896x over previous
//
#include <hip/hip_runtime.h>

#define N_NODES 100000
#define N_EDGES 1600000
#define D 64
#define N_GRAPHS 64
#define NBLK ((N_NODES + 255) / 256)   // 391 scan blocks

// ---------------- init: deg=1 (self loop), cnt=0, out=0 ----------------
__global__ void k_init(float* __restrict__ deg, int* __restrict__ cnt,
                       float* __restrict__ out) {
    int i = blockIdx.x * blockDim.x + threadIdx.x;
    if (i < N_NODES) { deg[i] = 1.0f; cnt[i] = 0; }
    if (i < N_GRAPHS * D) out[i] = 0.0f;
}

// ---------------- degree + in-edge count ----------------
__global__ void k_count_deg(const int* __restrict__ dst, const float* __restrict__ ew,
                            float* __restrict__ deg, int* __restrict__ cnt) {
    int e = blockIdx.x * blockDim.x + threadIdx.x;
    if (e < N_EDGES) {
        int d = dst[e];
        atomicAdd(&deg[d], ew[e]);
        atomicAdd(&cnt[d], 1);
    }
}

__global__ void k_dinv(float* __restrict__ deg) {
    int i = blockIdx.x * blockDim.x + threadIdx.x;
    if (i < N_NODES) {
        float d = deg[i];
        deg[i] = d > 0.f ? rsqrtf(d) : 0.f;
    }
}

// ---------------- exclusive scan of cnt -> rowptr (3 kernels) ----------------
__global__ void k_scan1(const int* __restrict__ cnt, int* __restrict__ partial,
                        int* __restrict__ bsums) {
    int t = threadIdx.x, b = blockIdx.x, i = b * 256 + t;
    int v = (i < N_NODES) ? cnt[i] : 0;
    int incl = v;
    int lane = t & 63;
#pragma unroll
    for (int off = 1; off < 64; off <<= 1) {
        int u = __shfl_up(incl, off);
        if (lane >= off) incl += u;
    }
    __shared__ int wsum[4];
    int w = t >> 6;
    if (lane == 63) wsum[w] = incl;
    __syncthreads();
    int add = 0;
    for (int k = 0; k < w; ++k) add += wsum[k];
    incl += add;
    if (i < N_NODES) partial[i] = incl;
    if (t == 255) bsums[b] = incl;
}

__global__ void k_scan2(int* __restrict__ bsums) {
    __shared__ int s[512];
    int t = threadIdx.x;
    s[t] = (t < NBLK) ? bsums[t] : 0;
    __syncthreads();
    for (int off = 1; off < 512; off <<= 1) {
        int u = (t >= off) ? s[t - off] : 0;
        __syncthreads();
        s[t] += u;
        __syncthreads();
    }
    if (t < NBLK) bsums[t] = (t == 0) ? 0 : s[t - 1];  // exclusive
}

__global__ void k_scan3(const int* __restrict__ partial, const int* __restrict__ cnt,
                        const int* __restrict__ bsums, int* __restrict__ rowptr,
                        int* __restrict__ cursor) {
    int i = blockIdx.x * 256 + threadIdx.x;
    if (i < N_NODES) {
        int excl = partial[i] - cnt[i] + bsums[blockIdx.x];
        rowptr[i] = excl;
        cursor[i] = excl;
    }
}

// ---------------- scatter edges into CSR (src, norm) grouped by dst ----------
__global__ void k_scatter(const int* __restrict__ src, const int* __restrict__ dst,
                          const float* __restrict__ ew, const float* __restrict__ dinv,
                          int* __restrict__ cursor, float2* __restrict__ csr) {
    int e = blockIdx.x * blockDim.x + threadIdx.x;
    if (e < N_EDGES) {
        int s = src[e];
        int d = dst[e];
        float nrm = dinv[s] * ew[e] * dinv[d];
        int pos = atomicAdd(&cursor[d], 1);
        csr[pos] = make_float2(__int_as_float(s), nrm);
    }
}

// ---------------- fused layer: row = gather(A_norm, in) ; r = relu(row@W + b) -
// LAYER==1: write r to outp[row].  LAYER==2: atomicAdd into pooled out[batch[row]].
template <int LAYER>
__global__ void k_layer(const float* __restrict__ in, const float* __restrict__ W,
                        const float* __restrict__ bias, const float* __restrict__ dinv,
                        const int* __restrict__ rowptr, const int* __restrict__ cnt,
                        const float2* __restrict__ csr, const int* __restrict__ batch,
                        float* __restrict__ outp) {
    __shared__ float Ws[D * D];
    for (int i = threadIdx.x; i < D * D; i += blockDim.x) Ws[i] = W[i];
    __syncthreads();

    const int lane = threadIdx.x & 63;
    int gw = (blockIdx.x * blockDim.x + threadIdx.x) >> 6;
    const int tw = (gridDim.x * blockDim.x) >> 6;
    const float bl = bias[lane];

    for (int row = gw; row < N_NODES; row += tw) {
        float di = dinv[row];
        float acc = in[row * D + lane] * (di * di);   // self-loop
        int st = rowptr[row];
        int dg = cnt[row];
        for (int j = 0; j < dg; ++j) {
            float2 sw = csr[st + j];
            acc = fmaf(in[__float_as_int(sw.x) * D + lane], sw.y, acc);
        }
        // GEMM: r[lane] = sum_k acc[k] * W[k][lane]
        float r = 0.f;
#pragma unroll
        for (int k = 0; k < D; ++k) {
            r = fmaf(__shfl(acc, k), Ws[k * D + lane], r);
        }
        r = fmaxf(r + bl, 0.f);
        if (LAYER == 1) {
            outp[row * D + lane] = r;
        } else {
            atomicAdd(&outp[batch[row] * D + lane], r);
        }
    }
}

// ---------------- finalize pool: divide by per-graph node count ----------------
__global__ void k_finalize(float* __restrict__ out, const int* __restrict__ batch) {
    int g = blockIdx.x;
    int lane = threadIdx.x;
    int lo = 0, hi = N_NODES;
    while (lo < hi) { int m = (lo + hi) >> 1; if (batch[m] < g) lo = m + 1; else hi = m; }
    int start = lo;
    hi = N_NODES;
    while (lo < hi) { int m = (lo + hi) >> 1; if (batch[m] < g + 1) lo = m + 1; else hi = m; }
    float c = (float)(lo - start);
    out[g * D + lane] /= fmaxf(c, 1.0f);
}

// ---------------- launch ----------------
extern "C" void kernel_launch(void* const* d_in, const int* in_sizes, int n_in,
                              void* d_out, int out_size, void* d_ws, size_t ws_size,
                              hipStream_t stream) {
    const float* x     = (const float*)d_in[0];
    const int*   ei    = (const int*)d_in[1];
    const int*   src   = ei;
    const int*   dst   = ei + N_EDGES;
    const int*   batch = (const int*)d_in[2];
    const float* ew    = (const float*)d_in[3];
    const float* W1    = (const float*)d_in[4];
    const float* b1    = (const float*)d_in[5];
    const float* W2    = (const float*)d_in[6];
    const float* b2    = (const float*)d_in[7];
    float* out = (float*)d_out;

    char* ws = (char*)d_ws;
    float*  bufA   = (float*)(ws);                    // 25.6 MB  h1
    float2* csr    = (float2*)(ws + 25600000);        // 12.8 MB  (src, norm)
    float*  deg    = (float*)(ws + 38400000);         // 400 KB   deg -> dinv
    int*    cnt    = (int*)(ws + 38800000);           // 400 KB
    int*    rowptr = (int*)(ws + 39200000);           // 400 KB
    int*    cursor = (int*)(ws + 39600000);           // 400 KB
    int*    bsums  = (int*)(ws + 40000000);           // 2 KB

    // normalization + CSR build
    k_init<<<NBLK, 256, 0, stream>>>(deg, cnt, out);
    k_count_deg<<<(N_EDGES + 255) / 256, 256, 0, stream>>>(dst, ew, deg, cnt);
    k_dinv<<<NBLK, 256, 0, stream>>>(deg);
    k_scan1<<<NBLK, 256, 0, stream>>>(cnt, rowptr, bsums);
    k_scan2<<<1, 512, 0, stream>>>(bsums);
    k_scan3<<<NBLK, 256, 0, stream>>>(rowptr, cnt, bsums, rowptr, cursor);
    k_scatter<<<(N_EDGES + 255) / 256, 256, 0, stream>>>(src, dst, ew, deg, cursor, csr);

    // layer 1: bufA = relu((A x) W1 + b1)
    k_layer<1><<<2048, 256, 0, stream>>>(x, W1, b1, deg, rowptr, cnt, csr, batch, bufA);
    // layer 2 + pool-sum: out[g] += relu((A bufA) W2 + b2)
    k_layer<2><<<2048, 256, 0, stream>>>(bufA, W2, b2, deg, rowptr, cnt, csr, batch, out);
    // mean
    k_finalize<<<N_GRAPHS, D, 0, stream>>>(out, batch);
}

// Round 3
// 568.763 us; speedup vs baseline: 1.8572x; 1.5612x over previous
//
#include <hip/hip_runtime.h>

#define N_NODES 100000
#define N_EDGES 1600000
#define D 64
#define N_GRAPHS 64
#define NBLK ((N_NODES + 255) / 256)   // 391 scan blocks

// ---------------- init: deg=1 (self loop), cnt=0, out=0 ----------------
__global__ void k_init(float* __restrict__ deg, int* __restrict__ cnt,
                       float* __restrict__ out) {
    int i = blockIdx.x * blockDim.x + threadIdx.x;
    if (i < N_NODES) { deg[i] = 1.0f; cnt[i] = 0; }
    if (i < N_GRAPHS * D) out[i] = 0.0f;
}

// ---------------- degree + in-edge count ----------------
__global__ void k_count_deg(const int* __restrict__ dst, const float* __restrict__ ew,
                            float* __restrict__ deg, int* __restrict__ cnt) {
    int e = blockIdx.x * blockDim.x + threadIdx.x;
    if (e < N_EDGES) {
        int d = dst[e];
        atomicAdd(&deg[d], ew[e]);
        atomicAdd(&cnt[d], 1);
    }
}

__global__ void k_dinv(float* __restrict__ deg) {
    int i = blockIdx.x * blockDim.x + threadIdx.x;
    if (i < N_NODES) {
        float d = deg[i];
        deg[i] = d > 0.f ? rsqrtf(d) : 0.f;
    }
}

// ---------------- exclusive scan of cnt -> rowptr (3 kernels) ----------------
__global__ void k_scan1(const int* __restrict__ cnt, int* __restrict__ partial,
                        int* __restrict__ bsums) {
    int t = threadIdx.x, b = blockIdx.x, i = b * 256 + t;
    int v = (i < N_NODES) ? cnt[i] : 0;
    int incl = v;
    int lane = t & 63;
#pragma unroll
    for (int off = 1; off < 64; off <<= 1) {
        int u = __shfl_up(incl, off);
        if (lane >= off) incl += u;
    }
    __shared__ int wsum[4];
    int w = t >> 6;
    if (lane == 63) wsum[w] = incl;
    __syncthreads();
    int add = 0;
    for (int k = 0; k < w; ++k) add += wsum[k];
    incl += add;
    if (i < N_NODES) partial[i] = incl;
    if (t == 255) bsums[b] = incl;
}

__global__ void k_scan2(int* __restrict__ bsums) {
    __shared__ int s[512];
    int t = threadIdx.x;
    s[t] = (t < NBLK) ? bsums[t] : 0;
    __syncthreads();
    for (int off = 1; off < 512; off <<= 1) {
        int u = (t >= off) ? s[t - off] : 0;
        __syncthreads();
        s[t] += u;
        __syncthreads();
    }
    if (t < NBLK) bsums[t] = (t == 0) ? 0 : s[t - 1];  // exclusive
}

__global__ void k_scan3(const int* __restrict__ partial, const int* __restrict__ cnt,
                        const int* __restrict__ bsums, int* __restrict__ rowptr,
                        int* __restrict__ cursor) {
    int i = blockIdx.x * 256 + threadIdx.x;
    if (i < N_NODES) {
        int excl = partial[i] - cnt[i] + bsums[blockIdx.x];
        rowptr[i] = excl;
        cursor[i] = excl;
    }
}

// ---------------- scatter edges into CSR (src, norm) grouped by dst ----------
__global__ void k_scatter(const int* __restrict__ src, const int* __restrict__ dst,
                          const float* __restrict__ ew, const float* __restrict__ dinv,
                          int* __restrict__ cursor, float2* __restrict__ csr) {
    int e = blockIdx.x * blockDim.x + threadIdx.x;
    if (e < N_EDGES) {
        int s = src[e];
        int d = dst[e];
        float nrm = dinv[s] * ew[e] * dinv[d];
        int pos = atomicAdd(&cursor[d], 1);
        csr[pos] = make_float2(__int_as_float(s), nrm);
    }
}

// ---------------- fused layer: row = gather(A_norm, in) ; r = relu(row@W + b) -
// LAYER==1: write r to outp[row].  LAYER==2: atomicAdd into pooled out[batch[row]].
template <int LAYER>
__global__ void k_layer(const float* __restrict__ in, const float* __restrict__ W,
                        const float* __restrict__ bias, const float* __restrict__ dinv,
                        const int* __restrict__ rowptr, const int* __restrict__ cnt,
                        const float2* __restrict__ csr, const int* __restrict__ batch,
                        float* __restrict__ outp) {
    __shared__ float Ws[D * D];
    for (int i = threadIdx.x; i < D * D; i += blockDim.x) Ws[i] = W[i];
    __syncthreads();

    const int lane = threadIdx.x & 63;
    int gw = (blockIdx.x * blockDim.x + threadIdx.x) >> 6;
    const int tw = (gridDim.x * blockDim.x) >> 6;
    const float bl = bias[lane];

    for (int row = gw; row < N_NODES; row += tw) {
        float di = dinv[row];
        float acc = in[row * D + lane] * (di * di);   // self-loop
        const int st = rowptr[row];
        const int dg = cnt[row];

        for (int base = 0; base < dg; base += 64) {
            int rem = dg - base;
            int n = rem < 64 ? rem : 64;
            // lane-cooperative coalesced CSR read, broadcast via shfl
            float2 my = make_float2(0.f, 0.f);
            if (lane < n) my = csr[st + base + lane];

            int j = 0;
            for (; j + 8 <= n; j += 8) {
                int   s0 = __float_as_int(__shfl(my.x, j + 0));
                int   s1 = __float_as_int(__shfl(my.x, j + 1));
                int   s2 = __float_as_int(__shfl(my.x, j + 2));
                int   s3 = __float_as_int(__shfl(my.x, j + 3));
                int   s4 = __float_as_int(__shfl(my.x, j + 4));
                int   s5 = __float_as_int(__shfl(my.x, j + 5));
                int   s6 = __float_as_int(__shfl(my.x, j + 6));
                int   s7 = __float_as_int(__shfl(my.x, j + 7));
                float w0 = __shfl(my.y, j + 0);
                float w1 = __shfl(my.y, j + 1);
                float w2 = __shfl(my.y, j + 2);
                float w3 = __shfl(my.y, j + 3);
                float w4 = __shfl(my.y, j + 4);
                float w5 = __shfl(my.y, j + 5);
                float w6 = __shfl(my.y, j + 6);
                float w7 = __shfl(my.y, j + 7);
                float v0 = in[s0 * D + lane];
                float v1 = in[s1 * D + lane];
                float v2 = in[s2 * D + lane];
                float v3 = in[s3 * D + lane];
                float v4 = in[s4 * D + lane];
                float v5 = in[s5 * D + lane];
                float v6 = in[s6 * D + lane];
                float v7 = in[s7 * D + lane];
                acc = fmaf(v0, w0, acc);
                acc = fmaf(v1, w1, acc);
                acc = fmaf(v2, w2, acc);
                acc = fmaf(v3, w3, acc);
                acc = fmaf(v4, w4, acc);
                acc = fmaf(v5, w5, acc);
                acc = fmaf(v6, w6, acc);
                acc = fmaf(v7, w7, acc);
            }
            for (; j < n; ++j) {
                int   s0 = __float_as_int(__shfl(my.x, j));
                float w0 = __shfl(my.y, j);
                acc = fmaf(in[s0 * D + lane], w0, acc);
            }
        }

        // GEMM: r[lane] = sum_k acc[k] * W[k][lane]  (4 partial chains)
        float r0 = 0.f, r1 = 0.f, r2 = 0.f, r3 = 0.f;
#pragma unroll
        for (int k = 0; k < D; k += 4) {
            r0 = fmaf(__shfl(acc, k + 0), Ws[(k + 0) * D + lane], r0);
            r1 = fmaf(__shfl(acc, k + 1), Ws[(k + 1) * D + lane], r1);
            r2 = fmaf(__shfl(acc, k + 2), Ws[(k + 2) * D + lane], r2);
            r3 = fmaf(__shfl(acc, k + 3), Ws[(k + 3) * D + lane], r3);
        }
        float r = fmaxf((r0 + r1) + (r2 + r3) + bl, 0.f);

        if (LAYER == 1) {
            outp[row * D + lane] = r;
        } else {
            atomicAdd(&outp[batch[row] * D + lane], r);
        }
    }
}

// ---------------- finalize pool: divide by per-graph node count ----------------
__global__ void k_finalize(float* __restrict__ out, const int* __restrict__ batch) {
    int g = blockIdx.x;
    int lane = threadIdx.x;
    int lo = 0, hi = N_NODES;
    while (lo < hi) { int m = (lo + hi) >> 1; if (batch[m] < g) lo = m + 1; else hi = m; }
    int start = lo;
    hi = N_NODES;
    while (lo < hi) { int m = (lo + hi) >> 1; if (batch[m] < g + 1) lo = m + 1; else hi = m; }
    float c = (float)(lo - start);
    out[g * D + lane] /= fmaxf(c, 1.0f);
}

// ---------------- launch ----------------
extern "C" void kernel_launch(void* const* d_in, const int* in_sizes, int n_in,
                              void* d_out, int out_size, void* d_ws, size_t ws_size,
                              hipStream_t stream) {
    const float* x     = (const float*)d_in[0];
    const int*   ei    = (const int*)d_in[1];
    const int*   src   = ei;
    const int*   dst   = ei + N_EDGES;
    const int*   batch = (const int*)d_in[2];
    const float* ew    = (const float*)d_in[3];
    const float* W1    = (const float*)d_in[4];
    const float* b1    = (const float*)d_in[5];
    const float* W2    = (const float*)d_in[6];
    const float* b2    = (const float*)d_in[7];
    float* out = (float*)d_out;

    char* ws = (char*)d_ws;
    float*  bufA   = (float*)(ws);                    // 25.6 MB  h1
    float2* csr    = (float2*)(ws + 25600000);        // 12.8 MB  (src, norm)
    float*  deg    = (float*)(ws + 38400000);         // 400 KB   deg -> dinv
    int*    cnt    = (int*)(ws + 38800000);           // 400 KB
    int*    rowptr = (int*)(ws + 39200000);           // 400 KB
    int*    cursor = (int*)(ws + 39600000);           // 400 KB
    int*    bsums  = (int*)(ws + 40000000);           // 2 KB

    // normalization + CSR build
    k_init<<<NBLK, 256, 0, stream>>>(deg, cnt, out);
    k_count_deg<<<(N_EDGES + 255) / 256, 256, 0, stream>>>(dst, ew, deg, cnt);
    k_dinv<<<NBLK, 256, 0, stream>>>(deg);
    k_scan1<<<NBLK, 256, 0, stream>>>(cnt, rowptr, bsums);
    k_scan2<<<1, 512, 0, stream>>>(bsums);
    k_scan3<<<NBLK, 256, 0, stream>>>(rowptr, cnt, bsums, rowptr, cursor);
    k_scatter<<<(N_EDGES + 255) / 256, 256, 0, stream>>>(src, dst, ew, deg, cursor, csr);

    // layer 1: bufA = relu((A x) W1 + b1)
    k_layer<1><<<2048, 256, 0, stream>>>(x, W1, b1, deg, rowptr, cnt, csr, batch, bufA);
    // layer 2 + pool-sum: out[g] += relu((A bufA) W2 + b2)
    k_layer<2><<<2048, 256, 0, stream>>>(bufA, W2, b2, deg, rowptr, cnt, csr, batch, out);
    // mean
    k_finalize<<<N_GRAPHS, D, 0, stream>>>(out, batch);
}